// Round 2
// baseline (198.276 us; speedup 1.0000x reference)
//
#include <hip/hip_runtime.h>

#define BB 16
#define CC 2
#define TT 1000
#define FF 257
#define NCHAIN (BB * CC * FF)          // 8224
#define RES_ELEMS ((size_t)BB * CC * TT * FF * 2)  // 16,448,000

// U=20, depth-2 pipeline: 2*U = 40 divides T=1000 exactly (25 outer iters).
constexpr int U = 20;

__global__ __launch_bounds__(256) void fnorm_kernel(
    const float* __restrict__ input,
    const float* __restrict__ weights,
    const float* __restrict__ bias,
    const float* __restrict__ alpha,
    const float* __restrict__ s1,
    float* __restrict__ out)
{
    int chain = blockIdx.x * blockDim.x + threadIdx.x;
    if (chain >= NCHAIN) return;

    int f  = chain % FF;
    int bc = chain / FF;
    int c  = bc % CC;
    int cf = c * FF + f;

    // float2 view: element (bc, t, f) at offset bc*T*F + t*F + f (float2 units)
    const float2* __restrict__ in2 = (const float2*)input + (size_t)bc * (TT * FF) + f;
    float2* __restrict__ out2      = (float2*)out        + (size_t)bc * (TT * FF) + f;

    float a  = 1.0f / (1.0f + __expf(-alpha[cf]));
    float om = 1.0f - a;
    float w  = weights[cf];
    float bi = bias[cf];
    float s  = s1[chain];

    float2 bufA[U], bufB[U];

    #pragma unroll
    for (int u = 0; u < U; ++u) bufA[u] = in2[(size_t)u * FF];

    for (int tb = 0; tb < TT; tb += 2 * U) {
        // prefetch batch B (t = tb+U .. tb+2U-1)
        #pragma unroll
        for (int u = 0; u < U; ++u) bufB[u] = in2[(size_t)(tb + U + u) * FF];

        // process batch A (t = tb .. tb+U-1)
        #pragma unroll
        for (int u = 0; u < U; ++u) {
            float2 x = bufA[u];
            float d2 = fmaf(x.x, x.x, x.y * x.y);
            s = fmaf(d2, a, s * om);
            float inv = __frsqrt_rn(s + 1e-16f) * w;
            float2 y;
            y.x = fmaf(x.x, inv, bi);
            y.y = fmaf(x.y, inv, bi);
            out2[(size_t)(tb + u) * FF] = y;
        }

        // prefetch next batch A (t = tb+2U .. tb+3U-1)
        if (tb + 2 * U < TT) {
            #pragma unroll
            for (int u = 0; u < U; ++u) bufA[u] = in2[(size_t)(tb + 2 * U + u) * FF];
        }

        // process batch B
        #pragma unroll
        for (int u = 0; u < U; ++u) {
            float2 x = bufB[u];
            float d2 = fmaf(x.x, x.x, x.y * x.y);
            s = fmaf(d2, a, s * om);
            float inv = __frsqrt_rn(s + 1e-16f) * w;
            float2 y;
            y.x = fmaf(x.x, inv, bi);
            y.y = fmaf(x.y, inv, bi);
            out2[(size_t)(tb + U + u) * FF] = y;
        }
    }

    // second output: s_last, flat after res
    out[RES_ELEMS + (size_t)chain] = s;
}

extern "C" void kernel_launch(void* const* d_in, const int* in_sizes, int n_in,
                              void* d_out, int out_size, void* d_ws, size_t ws_size,
                              hipStream_t stream) {
    const float* input   = (const float*)d_in[0];
    const float* weights = (const float*)d_in[1];
    const float* bias    = (const float*)d_in[2];
    const float* alpha   = (const float*)d_in[3];
    const float* s1      = (const float*)d_in[4];
    float* out = (float*)d_out;

    dim3 block(256);
    dim3 grid((NCHAIN + 255) / 256);   // 33 blocks
    hipLaunchKernelGGL(fnorm_kernel, grid, block, 0, stream,
                       input, weights, bias, alpha, s1, out);
}

// Round 3
// 135.901 us; speedup vs baseline: 1.4590x; 1.4590x over previous
//
#include <hip/hip_runtime.h>

#define BB 16
#define CC 2
#define TT 1000
#define FF 257
#define NCHAIN (BB * CC * FF)                       // 8224
#define RES_ELEMS ((size_t)BB * CC * TT * FF * 2)   // 16,448,000

#define CPB 16          // chains per block
#define KCH 20          // chunks per chain
#define LCH 50          // timesteps per chunk (20*50 = 1000)

// block = (16, 20) = 320 threads = 5 waves; grid = 8224/16 = 514 blocks (2/CU)
__global__ __launch_bounds__(320, 3) void fnorm_kernel(
    const float* __restrict__ input,
    const float* __restrict__ weights,
    const float* __restrict__ bias,
    const float* __restrict__ alpha,
    const float* __restrict__ s1,
    float* __restrict__ out)
{
    const int tx = threadIdx.x;          // chain within block
    const int k  = threadIdx.y;          // chunk index
    const int chain = blockIdx.x * CPB + tx;   // always < 8224 (514*16 exact)

    const int f  = chain % FF;
    const int bc = chain / FF;
    const int c  = bc % CC;
    const int cf = c * FF + f;

    const float2* __restrict__ in2 = (const float2*)input + (size_t)bc * (TT * FF) + f;
    float2* __restrict__ out2      = (float2*)out        + (size_t)bc * (TT * FF) + f;

    const float av = 1.0f / (1.0f + __expf(-alpha[cf]));
    const float om = 1.0f - av;
    const float w  = weights[cf];
    const float bi = bias[cf];

    const int t0 = k * LCH;

    // Phase A: load entire chunk into registers (100 VGPR buffer = deep
    // load pipeline), compute chunk-local scan-from-zero end value.
    float2 x[LCH];
    #pragma unroll
    for (int t = 0; t < LCH; ++t) x[t] = in2[(size_t)(t0 + t) * FF];

    float s = 0.0f;
    float p = 1.0f;     // om^LCH (uniform chunk length)
    #pragma unroll
    for (int t = 0; t < LCH; ++t) {
        float2 v = x[t];
        float d2 = fmaf(v.x, v.x, v.y * v.y);
        s = fmaf(d2, av, s * om);
        p *= om;
    }

    // Fix-up: serial combine of chunk summaries per chain.
    __shared__ float e_s[KCH][CPB];
    __shared__ float sinit_s[KCH][CPB];
    e_s[k][tx] = s;
    __syncthreads();
    if (k == 0) {
        float S = s1[chain];
        #pragma unroll
        for (int kk = 0; kk < KCH; ++kk) {
            sinit_s[kk][tx] = S;
            S = fmaf(S, p, e_s[kk][tx]);   // S*om^L + e_k
        }
        out[RES_ELEMS + (size_t)chain] = S;   // s_last
    }
    __syncthreads();

    // Phase B: rescan chunk from registers with correct initial state.
    s = sinit_s[k][tx];
    #pragma unroll
    for (int t = 0; t < LCH; ++t) {
        float2 v = x[t];
        float d2 = fmaf(v.x, v.x, v.y * v.y);
        s = fmaf(d2, av, s * om);
        float inv = __frsqrt_rn(s + 1e-16f) * w;
        float2 y;
        y.x = fmaf(v.x, inv, bi);
        y.y = fmaf(v.y, inv, bi);
        out2[(size_t)(t0 + t) * FF] = y;
    }
}

extern "C" void kernel_launch(void* const* d_in, const int* in_sizes, int n_in,
                              void* d_out, int out_size, void* d_ws, size_t ws_size,
                              hipStream_t stream) {
    const float* input   = (const float*)d_in[0];
    const float* weights = (const float*)d_in[1];
    const float* bias    = (const float*)d_in[2];
    const float* alpha   = (const float*)d_in[3];
    const float* s1      = (const float*)d_in[4];
    float* out = (float*)d_out;

    dim3 block(CPB, KCH);               // 320 threads
    dim3 grid(NCHAIN / CPB);            // 514 blocks
    hipLaunchKernelGGL(fnorm_kernel, grid, block, 0, stream,
                       input, weights, bias, alpha, s1, out);
}